// Round 13
// baseline (37.936 us; speedup 1.0000x reference)
//
#include <hip/hip_runtime.h>

#define WINDOW 11
#define H 512
#define W 512
#define OH 502            // H - WINDOW + 1
#define OW 502
#define NCH 3
#define BATCH 8
#define RSTRIPE 32
#define NSTRIPES 16       // 15 x 32 rows + 1 x 22 rows (both even trip counts)
#define NGRP 3            // col groups, float4 lanes: bases 0 / 244 / 256
#define WAVES_PER_IMG (NSTRIPES * NGRP)                 // 48
#define NWAVES (BATCH * NCH * WAVES_PER_IMG)            // 1152
#define WAVES_PER_BATCH (NCH * WAVES_PER_IMG)           // 144
#define NXCD 8
#define CHUNK (NWAVES / NXCD)                           // 144 = one batch per XCD

#define NPIX_PER_BATCH (3.0f * 502.0f * 502.0f)   // 756012

// ---- gfx9 DPP inclusive wave scan (64 lanes), VALU-pipe only ----
template <int CTRL, int RM>
__device__ __forceinline__ float scan_step(float x) {
    int s = __builtin_amdgcn_update_dpp(0, __builtin_bit_cast(int, x),
                                        CTRL, RM, 0xf, false);
    return x + __builtin_bit_cast(float, s);
}
__device__ __forceinline__ float wave_iscan(float x) {
    x = scan_step<0x111, 0xf>(x);   // row_shr:1
    x = scan_step<0x112, 0xf>(x);   // row_shr:2
    x = scan_step<0x114, 0xf>(x);   // row_shr:4
    x = scan_step<0x118, 0xf>(x);   // row_shr:8
    x = scan_step<0x142, 0xa>(x);   // row_bcast:15 -> rows 1,3
    x = scan_step<0x143, 0xc>(x);   // row_bcast:31 -> rows 2,3
    return x;
}

__device__ __forceinline__ float4 f4add(float4 a, float4 b) {
    return make_float4(a.x + b.x, a.y + b.y, a.z + b.z, a.w + b.w);
}
__device__ __forceinline__ float4 f4sub(float4 a, float4 b) {
    return make_float4(a.x - b.x, a.y - b.y, a.z - b.z, a.w - b.w);
}
__device__ __forceinline__ float4 shfl4(float4 v, int src) {
    return make_float4(__shfl(v.x, src, 64), __shfl(v.y, src, 64),
                       __shfl(v.z, src, 64), __shfl(v.w, src, 64));
}

__device__ __forceinline__ float ssim_from(float sx, float sy, float s2, float sxy) {
    const float n = 121.0f;
    const float inv_n = 1.0f / 121.0f;
    const float inv_nm1 = 1.0f / 120.0f;
    const float c1 = 1e-4f;   // (0.01)^2
    const float c2 = 9e-4f;   // (0.03)^2
    float mx  = sx * inv_n;
    float my  = sy * inv_n;
    float mxy = mx * my;
    float m2  = mx * mx + my * my;
    float cov = (sxy - n * mxy) * inv_nm1;   // covariance
    float v2  = (s2  - n * m2)  * inv_nm1;   // vx + vy
    float num = (2.f * mxy + c1) * (2.f * cov + c2);
    float den = (m2 + c1) * (v2 + c2);
    return num * __builtin_amdgcn_rcpf(den);  // den >= 9e-8, rel err ~1e-7
}

__global__ __launch_bounds__(64) void ssim_main(const float* __restrict__ x,
                                                const float* __restrict__ y,
                                                float* __restrict__ partials) {
    const int lane = threadIdx.x & 63;

    // XCD-chunked bijective swizzle: one batch (3 images, all grps+stripes)
    // per XCD -> all halo overlap and old-row re-reads are XCD-L2-local.
    const int wg    = blockIdx.x;               // 0..1151, round-robins XCDs
    const int w_lin = (wg % NXCD) * CHUNK + wg / NXCD;

    const int img = w_lin / WAVES_PER_IMG;      // b*NCH + c
    const int rem = w_lin % WAVES_PER_IMG;
    const int grp = rem / NSTRIPES;
    const int rs  = rem % NSTRIPES;             // stripe minor -> L2-contiguous

    const int i0 = rs * RSTRIPE;
    const int i1 = min(i0 + RSTRIPE, OH);       // 32 rows; stripe 15: 22 (even)
    // 4-aligned group bases; stage windows always inside [0,512)
    const int base  = (grp == 0) ? 0 : (grp == 1 ? 244 : 256);
    const int outLo = (grp == 0) ? 0 : (grp == 1 ? 246 : 490);
    const int outHi = (grp == 0) ? 245 : (grp == 1 ? 489 : 501);

    const int col = base + 4 * lane;            // this lane's 4 columns
    const bool m0a = (col     >= outLo) & (col     <= outHi);
    const bool m1a = (col + 1 >= outLo) & (col + 1 <= outHi);
    const bool m2a = (col + 2 >= outLo) & (col + 2 <= outHi);
    const bool m3a = (col + 3 >= outLo) & (col + 3 <= outHi);

    const float* __restrict__ xc = x + (size_t)img * H * W + col;
    const float* __restrict__ yc = y + (size_t)img * H * W + col;

    // --- init: per-column {sx, sy, sxx+syy, sxy} sums for rows i0..i0+10 ---
    float4 v0 = make_float4(0.f, 0.f, 0.f, 0.f);   // col+0
    float4 v1 = v0, v2 = v0, v3 = v0;              // col+1..3
#pragma unroll
    for (int r = 0; r < WINDOW; ++r) {
        float4 a = *(const float4*)(xc + (size_t)(i0 + r) * W);
        float4 b = *(const float4*)(yc + (size_t)(i0 + r) * W);
        v0.x += a.x; v0.y += b.x; v0.z += a.x * a.x + b.x * b.x; v0.w += a.x * b.x;
        v1.x += a.y; v1.y += b.y; v1.z += a.y * a.y + b.y * b.y; v1.w += a.y * b.y;
        v2.x += a.z; v2.y += b.z; v2.z += a.z * a.z + b.z * b.z; v2.w += a.z * b.z;
        v3.x += a.w; v3.y += b.w; v3.z += a.w * a.w + b.w * b.w; v3.w += a.w * b.w;
    }

#define LD(j, xo, yo, xn, yn) do {                                  \
        int jc_ = min((j), H - 1);                                   \
        int rn_ = min((j) + WINDOW, H - 1);                          \
        xo = *(const float4*)(xc + (size_t)jc_ * W);                 \
        yo = *(const float4*)(yc + (size_t)jc_ * W);                 \
        xn = *(const float4*)(xc + (size_t)rn_ * W);                 \
        yn = *(const float4*)(yc + (size_t)rn_ * W);                 \
    } while (0)

    // one column's slide update: v <- v + contrib(new) - contrib(old)
#define SL1(v, cN, cO, dN, dO) do {                                  \
        v.x += cN - cO;                                              \
        v.y += dN - dO;                                              \
        v.z += cN * cN + dN * dN - cO * cO - dO * dO;                \
        v.w += cN * dN - cO * dO;                                    \
    } while (0)

#define SLIDE(xo, yo, xn, yn) do {                                   \
        SL1(v0, xn.x, xo.x, yn.x, yo.x);                             \
        SL1(v1, xn.y, xo.y, yn.y, yo.y);                             \
        SL1(v2, xn.z, xo.z, yn.z, yo.z);                             \
        SL1(v3, xn.w, xo.w, yn.w, yo.w);                             \
    } while (0)

    float acc = 0.f;

    // Window sums via wave scan. For lane l (T = v0+v1+v2+v3, S = iscan(T)):
    //   L = S - T; m0 = L+v0; m01 = m0+v1; m012 = m01+v2
    //   W[col+0] = m012[l+2] - L       W[col+1] = S[l+2]   - m0
    //   W[col+2] = m0[l+3]   - m01     W[col+3] = m01[l+3] - m012
#define COMPUTE() do {                                                        \
        float4 T = f4add(f4add(v0, v1), f4add(v2, v3));                       \
        float4 S = make_float4(wave_iscan(T.x), wave_iscan(T.y),              \
                               wave_iscan(T.z), wave_iscan(T.w));             \
        float4 L    = f4sub(S, T);                                            \
        float4 p0   = f4add(L, v0);                                           \
        float4 p01  = f4add(p0, v1);                                          \
        float4 p012 = f4add(p01, v2);                                         \
        float4 A012 = shfl4(p012, lane + 2);                                  \
        float4 AS   = shfl4(S,    lane + 2);                                  \
        float4 B0   = shfl4(p0,   lane + 3);                                  \
        float4 B01  = shfl4(p01,  lane + 3);                                  \
        float4 W0 = f4sub(A012, L);                                           \
        float4 W1 = f4sub(AS,   p0);                                          \
        float4 W2 = f4sub(B0,   p01);                                         \
        float4 W3 = f4sub(B01,  p012);                                        \
        acc += m0a ? ssim_from(W0.x, W0.y, W0.z, W0.w) : 0.f;                 \
        acc += m1a ? ssim_from(W1.x, W1.y, W1.z, W1.w) : 0.f;                 \
        acc += m2a ? ssim_from(W2.x, W2.y, W2.z, W2.w) : 0.f;                 \
        acc += m3a ? ssim_from(W3.x, W3.y, W3.z, W3.w) : 0.f;                 \
    } while (0)

    // --- depth-2 software-pipelined main loop (best known structure, R6) ---
    float4 xoA, yoA, xnA, ynA, xoB, yoB, xnB, ynB;
    LD(i0,     xoA, yoA, xnA, ynA);
    LD(i0 + 1, xoB, yoB, xnB, ynB);
    for (int i = i0; i < i1; i += 2) {
        COMPUTE();                       // row i
        SLIDE(xoA, yoA, xnA, ynA);       // -> window for row i+1
        LD(i + 2, xoA, yoA, xnA, ynA);   // prefetch iter i+2 (row clamped)
        COMPUTE();                       // row i+1
        SLIDE(xoB, yoB, xnB, ynB);       // -> window for row i+2
        LD(i + 3, xoB, yoB, xnB, ynB);   // prefetch iter i+3 (row clamped)
    }

    // --- per-wave reduction (fixed order, deterministic), no atomics ---
    for (int off = 32; off > 0; off >>= 1)
        acc += __shfl_down(acc, off, 64);
    if (lane == 0) partials[w_lin] = acc;   // batch-contiguous layout
}

__global__ __launch_bounds__(256) void ssim_reduce(const float* __restrict__ partials,
                                                   float* __restrict__ out) {
    const int b = blockIdx.x;              // one block per batch element
    const int t = threadIdx.x;
    float s = 0.f;
    if (t < WAVES_PER_BATCH)               // 144 per batch
        s = partials[b * WAVES_PER_BATCH + t];
    for (int off = 32; off > 0; off >>= 1)
        s += __shfl_down(s, off, 64);
    __shared__ float red[4];
    int wid = t >> 6, lane = t & 63;
    if (lane == 0) red[wid] = s;
    __syncthreads();
    if (t == 0) {
        float tot = (red[0] + red[1]) + (red[2] + red[3]);
        out[b] = (1.0f - tot / NPIX_PER_BATCH) * 0.5f;
    }
}

extern "C" void kernel_launch(void* const* d_in, const int* in_sizes, int n_in,
                              void* d_out, int out_size, void* d_ws, size_t ws_size,
                              hipStream_t stream) {
    const float* x = (const float*)d_in[0];
    const float* y = (const float*)d_in[1];
    float* out      = (float*)d_out;
    float* partials = (float*)d_ws;   // 1152 floats, fully overwritten each call

    ssim_main<<<NWAVES, 64, 0, stream>>>(x, y, partials);
    ssim_reduce<<<BATCH, 256, 0, stream>>>(partials, out);
}

// Round 14
// 26.889 us; speedup vs baseline: 1.4109x; 1.4109x over previous
//
#include <hip/hip_runtime.h>

#define WINDOW 11
#define H 512
#define W 512
#define OH 502            // H - WINDOW + 1
#define OW 502
#define NCH 3
#define BATCH 8
#define RSTRIPE 33        // 3 x 11 -> FIFO slot = unroll index (static)
#define NSTRIPES 16       // 15 x 33 rows + 1 x 7 live rows (one masked pass)
#define NGRP 5            // col groups: 4 x 118 outputs + 1 x 30 (float2 lanes)
#define GRPW 118          // output cols per full group (64 lanes * 2 - 10 halo)
#define WAVES_PER_IMG (NSTRIPES * NGRP)                 // 80
#define NWAVES (BATCH * NCH * WAVES_PER_IMG)            // 1920
#define WAVES_PER_BATCH (NCH * WAVES_PER_IMG)           // 240
#define NXCD 8
#define CHUNK (NWAVES / NXCD)                           // 240 = one batch per XCD

#define NPIX_PER_BATCH (3.0f * 502.0f * 502.0f)   // 756012

// ---- gfx9 DPP inclusive wave scan (64 lanes), VALU-pipe only ----
template <int CTRL, int RM>
__device__ __forceinline__ float scan_step(float x) {
    int s = __builtin_amdgcn_update_dpp(0, __builtin_bit_cast(int, x),
                                        CTRL, RM, 0xf, false);
    return x + __builtin_bit_cast(float, s);
}
__device__ __forceinline__ float wave_iscan(float x) {
    x = scan_step<0x111, 0xf>(x);   // row_shr:1
    x = scan_step<0x112, 0xf>(x);   // row_shr:2
    x = scan_step<0x114, 0xf>(x);   // row_shr:4
    x = scan_step<0x118, 0xf>(x);   // row_shr:8
    x = scan_step<0x142, 0xa>(x);   // row_bcast:15 -> rows 1,3
    x = scan_step<0x143, 0xc>(x);   // row_bcast:31 -> rows 2,3
    return x;
}

__device__ __forceinline__ float ssim_from(float sx, float sy, float s2, float sxy) {
    const float n = 121.0f;
    const float inv_n = 1.0f / 121.0f;
    const float inv_nm1 = 1.0f / 120.0f;
    const float c1 = 1e-4f;   // (0.01)^2
    const float c2 = 9e-4f;   // (0.03)^2
    float mx  = sx * inv_n;
    float my  = sy * inv_n;
    float mxy = mx * my;
    float m2  = mx * mx + my * my;
    float cov = (sxy - n * mxy) * inv_nm1;   // covariance
    float v2  = (s2  - n * m2)  * inv_nm1;   // vx + vy
    float num = (2.f * mxy + c1) * (2.f * cov + c2);
    float den = (m2 + c1) * (v2 + c2);
    return num * __builtin_amdgcn_rcpf(den);  // den >= 9e-8, rel err ~1e-7
}

__global__ __launch_bounds__(64) void ssim_main(const float* __restrict__ x,
                                                const float* __restrict__ y,
                                                float* __restrict__ partials) {
    const int lane = threadIdx.x & 63;

    // XCD-chunked bijective swizzle: one batch (3 images) per XCD -> the only
    // remaining reuse (cross-stripe halo rows) is XCD-L2-local.
    const int wg    = blockIdx.x;               // 0..1919, round-robins XCDs
    const int w_lin = (wg % NXCD) * CHUNK + wg / NXCD;

    const int img = w_lin / WAVES_PER_IMG;      // b*NCH + c
    const int rem = w_lin % WAVES_PER_IMG;
    const int grp = rem / NSTRIPES;
    const int rs  = rem % NSTRIPES;             // stripe minor -> L2-contiguous

    const int i0 = rs * RSTRIPE;
    const int i1 = min(i0 + RSTRIPE, OH);       // 33 rows; stripe 15: 7 live
    const int cstart = grp * GRPW;              // first staged/output col
    const int outw   = min(GRPW, OW - cstart);  // 118 or 30
    // clamped column pair: out-of-range lanes read real (unused) data
    const int c0 = min(cstart + 2 * lane, W - 2);
    const bool tapActive = (2 * lane < outw);

    const float* __restrict__ xc = x + (size_t)img * H * W + c0;
    const float* __restrict__ yc = y + (size_t)img * H * W + c0;

    // --- 11-row register FIFO: each input row is loaded exactly ONCE ---
    float2 fx[11], fy[11];
    float4 v0 = make_float4(0.f, 0.f, 0.f, 0.f);
    float4 v1 = make_float4(0.f, 0.f, 0.f, 0.f);
#pragma unroll
    for (int r = 0; r < WINDOW; ++r) {
        float2 a = *(const float2*)(xc + (size_t)(i0 + r) * W);
        float2 b = *(const float2*)(yc + (size_t)(i0 + r) * W);
        fx[r] = a; fy[r] = b;
        v0.x += a.x; v0.y += b.x; v0.z += a.x * a.x + b.x * b.x; v0.w += a.x * b.x;
        v1.x += a.y; v1.y += b.y; v1.z += a.y * a.y + b.y * b.y; v1.w += a.y * b.y;
    }

    // incoming row buffer (row i+11), loaded one iteration ahead
    float2 nx, ny;
#define LDNEW(j) do {                                                \
        int jc_ = min((j), H - 1);                                   \
        nx = *(const float2*)(xc + (size_t)jc_ * W);                 \
        ny = *(const float2*)(yc + (size_t)jc_ * W);                 \
    } while (0)

    // slide: old row from FIFO slot u (registers), new row from (nx, ny)
#define SLIDE(u) do {                                                 \
        v0.x += nx.x - fx[u].x;                                       \
        v0.y += ny.x - fy[u].x;                                       \
        v0.z += nx.x * nx.x + ny.x * ny.x                             \
              - fx[u].x * fx[u].x - fy[u].x * fy[u].x;                \
        v0.w += nx.x * ny.x - fx[u].x * fy[u].x;                      \
        v1.x += nx.y - fx[u].y;                                       \
        v1.y += ny.y - fy[u].y;                                       \
        v1.z += nx.y * nx.y + ny.y * ny.y                             \
              - fx[u].y * fx[u].y - fy[u].y * fy[u].y;                \
        v1.w += nx.y * ny.y - fx[u].y * fy[u].y;                      \
        fx[u] = nx; fy[u] = ny;                                       \
    } while (0)

    float acc = 0.f;

#define COMPUTE(rowActive) do {                                               \
        float Tx = v0.x + v1.x, Ty = v0.y + v1.y;                             \
        float Tz = v0.z + v1.z, Tw = v0.w + v1.w;                             \
        float Sx = wave_iscan(Tx), Sy = wave_iscan(Ty);                       \
        float Sz = wave_iscan(Tz), Sw = wave_iscan(Tw);                       \
        int src = lane + 5;                                                   \
        float Ax = __shfl(Sx, src, 64), Ay = __shfl(Sy, src, 64);             \
        float Az = __shfl(Sz, src, 64), Aw = __shfl(Sw, src, 64);             \
        float Bx = __shfl(v1.x, src, 64), By = __shfl(v1.y, src, 64);         \
        float Bz = __shfl(v1.z, src, 64), Bw = __shfl(v1.w, src, 64);         \
        if (tapActive & (rowActive)) {                                        \
            acc += ssim_from(Ax - Bx - Sx + Tx, Ay - By - Sy + Ty,            \
                             Az - Bz - Sz + Tz, Aw - Bw - Sw + Tw);           \
            acc += ssim_from(Ax - Sx + v1.x, Ay - Sy + v1.y,                  \
                             Az - Sz + v1.z, Aw - Sw + v1.w);                 \
        }                                                                     \
    } while (0)

    // --- main loop: unroll 11 so the FIFO slot index is static ---
    LDNEW(i0 + WINDOW);                   // prefetch first incoming row
    for (int base = i0; base < i1; base += 11) {
#pragma unroll
        for (int u = 0; u < 11; ++u) {
            const int i = base + u;
            COMPUTE(i < i1);              // window sums + SSIM for row i
            SLIDE(u);                     // retire row i, absorb row i+11
            LDNEW(i + WINDOW + 1);        // prefetch next incoming (clamped)
        }
    }

    // --- per-wave reduction (fixed order, deterministic), no atomics ---
    for (int off = 32; off > 0; off >>= 1)
        acc += __shfl_down(acc, off, 64);
    if (lane == 0) partials[w_lin] = acc;   // batch-contiguous layout
}

__global__ __launch_bounds__(256) void ssim_reduce(const float* __restrict__ partials,
                                                   float* __restrict__ out) {
    const int b = blockIdx.x;              // one block per batch element
    const int t = threadIdx.x;
    float s = 0.f;
    if (t < WAVES_PER_BATCH)               // 240 per batch
        s = partials[b * WAVES_PER_BATCH + t];
    for (int off = 32; off > 0; off >>= 1)
        s += __shfl_down(s, off, 64);
    __shared__ float red[4];
    int wid = t >> 6, lane = t & 63;
    if (lane == 0) red[wid] = s;
    __syncthreads();
    if (t == 0) {
        float tot = (red[0] + red[1]) + (red[2] + red[3]);
        out[b] = (1.0f - tot / NPIX_PER_BATCH) * 0.5f;
    }
}

extern "C" void kernel_launch(void* const* d_in, const int* in_sizes, int n_in,
                              void* d_out, int out_size, void* d_ws, size_t ws_size,
                              hipStream_t stream) {
    const float* x = (const float*)d_in[0];
    const float* y = (const float*)d_in[1];
    float* out      = (float*)d_out;
    float* partials = (float*)d_ws;   // 1920 floats, fully overwritten each call

    ssim_main<<<NWAVES, 64, 0, stream>>>(x, y, partials);
    ssim_reduce<<<BATCH, 256, 0, stream>>>(partials, out);
}